// Round 1
// baseline (649.928 us; speedup 1.0000x reference)
//
#include <hip/hip_runtime.h>
#include <math.h>

#define HB 256
#define ROWS 32

// LDS layout (floats):
//   bufA : 32*264 = 8448   (h1 raw/normalized; later logits+softmax p)
//   bufB : 32*136 = 4352   (h2)
//   reg1 : 3232            (x staging -> h3 (stride 68) -> proj (stride 101))
//   qs   : 104, rwL/bdL/muL/rsL : 32 each
// total 16264 floats = 65056 B -> 2 blocks/CU

template<int STRIDE, int N>
__device__ __forceinline__ void ln_stats(const float* __restrict__ buf,
                                         float* __restrict__ muL,
                                         float* __restrict__ rsL, int t)
{
  const int rid = t >> 3;          // 32 rows x 8 threads
  const int sub = t & 7;
  float s = 0.f, s2 = 0.f;
#pragma unroll
  for (int i = 0; i < N / 8; ++i) {
    const float v = buf[rid * STRIDE + sub + 8 * i];
    s += v; s2 += v * v;
  }
  s += __shfl_xor(s, 4); s2 += __shfl_xor(s2, 4);
  s += __shfl_xor(s, 2); s2 += __shfl_xor(s2, 2);
  s += __shfl_xor(s, 1); s2 += __shfl_xor(s2, 1);
  if (sub == 0) {
    const float invN = 1.f / (float)N;
    const float mu = s * invN;
    const float var = s2 * invN - mu * mu;
    muL[rid] = mu;
    rsL[rid] = rsqrtf(var + 1e-5f);
  }
}

__global__ __launch_bounds__(HB, 2)
void sacq_kernel(const float* __restrict__ obs,  const float* __restrict__ act,
                 const float* __restrict__ rew,  const float* __restrict__ boot,
                 const float* __restrict__ disc, const float* __restrict__ qsup,
                 const float* __restrict__ W1, const float* __restrict__ b1,
                 const float* __restrict__ g1, const float* __restrict__ be1,
                 const float* __restrict__ W2, const float* __restrict__ b2,
                 const float* __restrict__ g2, const float* __restrict__ be2,
                 const float* __restrict__ W3, const float* __restrict__ b3,
                 const float* __restrict__ g3, const float* __restrict__ be3,
                 const float* __restrict__ W4, const float* __restrict__ b4,
                 float* __restrict__ out)
{
  __shared__ float sm[16264];
  float* bufA = sm;            // stride 264
  float* bufB = sm + 8448;     // stride 136
  float* reg1 = sm + 12800;    // x(stride 80) / h3(stride 68) / proj(stride 101)
  float* qs   = sm + 16032;
  float* rwL  = sm + 16136;
  float* bdL  = sm + 16168;
  float* muL  = sm + 16200;
  float* rsL  = sm + 16232;

  const int t = threadIdx.x;
  const long row0 = (long)blockIdx.x * ROWS;

  // ---- stage x = concat(obs, actions) into reg1 (stride 80); preload consts
  {
    const float* ob = obs + row0 * 60;
    for (int idx = t; idx < ROWS * 60; idx += HB) {
      const int r = idx / 60, c = idx - r * 60;
      reg1[r * 80 + c] = ob[idx];
    }
    const float* ac = act + row0 * 20;
    for (int idx = t; idx < ROWS * 20; idx += HB) {
      const int r = idx / 20, c = idx - r * 20;
      reg1[r * 80 + 60 + c] = ac[idx];
    }
    if (t < 101) qs[t] = qsup[t];
    if (t < ROWS) {
      rwL[t] = rew[row0 + t];
      bdL[t] = boot[row0 + t] * disc[row0 + t];
    }
  }
  __syncthreads();

  // ---- Layer 1: [32x80] @ [80x256] -> bufA, LN(256)+SiLU
  {
    const int c0 = 2 * (t & 127);
    const int rb = (t >> 7) * 16;
    float accx[16], accy[16];
    {
      const float2 bb = *(const float2*)&b1[c0];
#pragma unroll
      for (int r = 0; r < 16; ++r) { accx[r] = bb.x; accy[r] = bb.y; }
    }
    for (int k = 0; k < 80; k += 4) {
      const float2 w0 = *(const float2*)&W1[(k + 0) * 256 + c0];
      const float2 w1 = *(const float2*)&W1[(k + 1) * 256 + c0];
      const float2 w2 = *(const float2*)&W1[(k + 2) * 256 + c0];
      const float2 w3 = *(const float2*)&W1[(k + 3) * 256 + c0];
#pragma unroll
      for (int r = 0; r < 16; ++r) {
        const float4 x = *(const float4*)&reg1[(rb + r) * 80 + k];
        accx[r] += x.x * w0.x + x.y * w1.x + x.z * w2.x + x.w * w3.x;
        accy[r] += x.x * w0.y + x.y * w1.y + x.z * w2.y + x.w * w3.y;
      }
    }
#pragma unroll
    for (int r = 0; r < 16; ++r)
      *(float2*)&bufA[(rb + r) * 264 + c0] = make_float2(accx[r], accy[r]);
    __syncthreads();
    ln_stats<264, 256>(bufA, muL, rsL, t);
    __syncthreads();
    const float2 g  = *(const float2*)&g1[c0];
    const float2 be = *(const float2*)&be1[c0];
#pragma unroll
    for (int r = 0; r < 16; ++r) {
      const float mu = muL[rb + r], rs = rsL[rb + r];
      float vx = (accx[r] - mu) * rs * g.x + be.x;
      float vy = (accy[r] - mu) * rs * g.y + be.y;
      vx = vx / (1.f + expf(-vx));
      vy = vy / (1.f + expf(-vy));
      *(float2*)&bufA[(rb + r) * 264 + c0] = make_float2(vx, vy);
    }
  }
  __syncthreads();

  // ---- Layer 2: [32x256] @ [256x128] -> bufB, LN(128)+SiLU
  {
    const int c0 = 2 * (t & 63);
    const int rb = (t >> 6) * 8;
    float accx[8], accy[8];
    {
      const float2 bb = *(const float2*)&b2[c0];
#pragma unroll
      for (int r = 0; r < 8; ++r) { accx[r] = bb.x; accy[r] = bb.y; }
    }
    for (int k = 0; k < 256; k += 4) {
      const float2 w0 = *(const float2*)&W2[(k + 0) * 128 + c0];
      const float2 w1 = *(const float2*)&W2[(k + 1) * 128 + c0];
      const float2 w2 = *(const float2*)&W2[(k + 2) * 128 + c0];
      const float2 w3 = *(const float2*)&W2[(k + 3) * 128 + c0];
#pragma unroll
      for (int r = 0; r < 8; ++r) {
        const float4 h = *(const float4*)&bufA[(rb + r) * 264 + k];
        accx[r] += h.x * w0.x + h.y * w1.x + h.z * w2.x + h.w * w3.x;
        accy[r] += h.x * w0.y + h.y * w1.y + h.z * w2.y + h.w * w3.y;
      }
    }
#pragma unroll
    for (int r = 0; r < 8; ++r)
      *(float2*)&bufB[(rb + r) * 136 + c0] = make_float2(accx[r], accy[r]);
    __syncthreads();
    ln_stats<136, 128>(bufB, muL, rsL, t);
    __syncthreads();
    const float2 g  = *(const float2*)&g2[c0];
    const float2 be = *(const float2*)&be2[c0];
#pragma unroll
    for (int r = 0; r < 8; ++r) {
      const float mu = muL[rb + r], rs = rsL[rb + r];
      float vx = (accx[r] - mu) * rs * g.x + be.x;
      float vy = (accy[r] - mu) * rs * g.y + be.y;
      vx = vx / (1.f + expf(-vx));
      vy = vy / (1.f + expf(-vy));
      *(float2*)&bufB[(rb + r) * 136 + c0] = make_float2(vx, vy);
    }
  }
  __syncthreads();

  // ---- Layer 3: [32x128] @ [128x64] -> reg1 (stride 68), LN(64)+SiLU
  {
    const int c0 = 2 * (t & 31);
    const int rb = (t >> 5) * 4;
    float accx[4], accy[4];
    {
      const float2 bb = *(const float2*)&b3[c0];
#pragma unroll
      for (int r = 0; r < 4; ++r) { accx[r] = bb.x; accy[r] = bb.y; }
    }
    for (int k = 0; k < 128; k += 4) {
      const float2 w0 = *(const float2*)&W3[(k + 0) * 64 + c0];
      const float2 w1 = *(const float2*)&W3[(k + 1) * 64 + c0];
      const float2 w2 = *(const float2*)&W3[(k + 2) * 64 + c0];
      const float2 w3 = *(const float2*)&W3[(k + 3) * 64 + c0];
#pragma unroll
      for (int r = 0; r < 4; ++r) {
        const float4 h = *(const float4*)&bufB[(rb + r) * 136 + k];
        accx[r] += h.x * w0.x + h.y * w1.x + h.z * w2.x + h.w * w3.x;
        accy[r] += h.x * w0.y + h.y * w1.y + h.z * w2.y + h.w * w3.y;
      }
    }
#pragma unroll
    for (int r = 0; r < 4; ++r)
      *(float2*)&reg1[(rb + r) * 68 + c0] = make_float2(accx[r], accy[r]);
    __syncthreads();
    ln_stats<68, 64>(reg1, muL, rsL, t);
    __syncthreads();
    const float2 g  = *(const float2*)&g3[c0];
    const float2 be = *(const float2*)&be3[c0];
#pragma unroll
    for (int r = 0; r < 4; ++r) {
      const float mu = muL[rb + r], rs = rsL[rb + r];
      float vx = (accx[r] - mu) * rs * g.x + be.x;
      float vy = (accy[r] - mu) * rs * g.y + be.y;
      vx = vx / (1.f + expf(-vx));
      vy = vy / (1.f + expf(-vy));
      *(float2*)&reg1[(rb + r) * 68 + c0] = make_float2(vx, vy);
    }
  }
  __syncthreads();

  // ---- Layer 4: [32x64] @ [64x101] -> logits into bufA (stride 264)
  {
    const bool act4 = (t < 202);
    const int j4 = (t < 101) ? t : (t - 101);
    const int rb4 = (t < 101) ? 0 : 16;
    if (act4) {
      float accl[16];
      const float bj = b4[j4];
#pragma unroll
      for (int r = 0; r < 16; ++r) accl[r] = bj;
      for (int k = 0; k < 64; k += 4) {
        const float w0 = W4[(k + 0) * 101 + j4];
        const float w1 = W4[(k + 1) * 101 + j4];
        const float w2 = W4[(k + 2) * 101 + j4];
        const float w3 = W4[(k + 3) * 101 + j4];
#pragma unroll
        for (int r = 0; r < 16; ++r) {
          const float4 h = *(const float4*)&reg1[(rb4 + r) * 68 + k];
          accl[r] += h.x * w0 + h.y * w1 + h.z * w2 + h.w * w3;
        }
      }
#pragma unroll
      for (int r = 0; r < 16; ++r) bufA[(rb4 + r) * 264 + j4] = accl[r];
    }
  }
  __syncthreads();

  // ---- Softmax over 101 atoms per row (in-place in bufA); zero proj (reg1)
  {
    const int rid = t >> 3;
    const int sub = t & 7;
    float lv[13];
    float mx = -3.4e38f;
#pragma unroll
    for (int i = 0; i < 13; ++i) {
      const int j = sub + 8 * i;
      lv[i] = (j < 101) ? bufA[rid * 264 + j] : -3.4e38f;
      mx = fmaxf(mx, lv[i]);
    }
    mx = fmaxf(mx, __shfl_xor(mx, 4));
    mx = fmaxf(mx, __shfl_xor(mx, 2));
    mx = fmaxf(mx, __shfl_xor(mx, 1));
    float se = 0.f;
#pragma unroll
    for (int i = 0; i < 13; ++i) {
      lv[i] = expf(lv[i] - mx);
      se += lv[i];
    }
    se += __shfl_xor(se, 4);
    se += __shfl_xor(se, 2);
    se += __shfl_xor(se, 1);
#pragma unroll
    for (int i = 0; i < 13; ++i) {
      const int j = sub + 8 * i;
      if (j < 101) bufA[rid * 264 + j] = lv[i] / se;
    }
  }
  for (int idx = t; idx < ROWS * 101; idx += HB) reg1[idx] = 0.f;
  __syncthreads();

  // ---- Categorical projection: scatter within each row into reg1 (stride 101)
  {
    const int rid = t >> 3;
    const int sub = t & 7;
    const float rw = rwL[rid], bd = bdL[rid];
#pragma unroll
    for (int i = 0; i < 13; ++i) {
      const int a = sub + 8 * i;
      if (a < 101) {
        const float p = bufA[rid * 264 + a];
        float tz = rw + bd * qs[a];
        tz = fminf(fmaxf(tz, -10.f), 10.f);
        const float b_ = (tz + 10.f) / 0.2f;
        const float fl = floorf(b_), cl = ceilf(b_);
        int li = (int)fl, ui = (int)cl;
        if (ui == li) { if (li > 0) li -= 1; else ui += 1; }
        const float lw = p * ((float)ui - b_);
        const float uw = p * (b_ - (float)li);
        atomicAdd(&reg1[rid * 101 + li], lw);
        atomicAdd(&reg1[rid * 101 + ui], uw);
      }
    }
  }
  __syncthreads();

  // ---- Coalesced float4 writeout (proj is contiguous [32][101])
  {
    float4* o4 = (float4*)(out + row0 * 101);
    const float4* p4 = (const float4*)reg1;
    for (int idx = t; idx < (ROWS * 101) / 4; idx += HB) o4[idx] = p4[idx];
  }
}

extern "C" void kernel_launch(void* const* d_in, const int* in_sizes, int n_in,
                              void* d_out, int out_size, void* d_ws, size_t ws_size,
                              hipStream_t stream)
{
  const int B = in_sizes[2];  // rewards has B elements
  dim3 grid(B / ROWS), block(HB);
  sacq_kernel<<<grid, block, 0, stream>>>(
      (const float*)d_in[0],  (const float*)d_in[1],  (const float*)d_in[2],
      (const float*)d_in[3],  (const float*)d_in[4],  (const float*)d_in[5],
      (const float*)d_in[6],  (const float*)d_in[7],  (const float*)d_in[8],
      (const float*)d_in[9],  (const float*)d_in[10], (const float*)d_in[11],
      (const float*)d_in[12], (const float*)d_in[13], (const float*)d_in[14],
      (const float*)d_in[15], (const float*)d_in[16], (const float*)d_in[17],
      (const float*)d_in[18], (const float*)d_in[19], (float*)d_out);
}

// Round 2
// 356.756 us; speedup vs baseline: 1.8218x; 1.8218x over previous
//
#include <hip/hip_runtime.h>
#include <math.h>

typedef __bf16 bf16x8 __attribute__((ext_vector_type(8)));
typedef float f32x4 __attribute__((ext_vector_type(4)));

// ---------------- weight conversion: fp32 -> bf16 frag-major in d_ws ----------
// Layers (padded K x N): L1 96x256 (48 frags), L2 256x128 (64), L3 128x64 (16),
// L4 64x128 (16, N 101->128 zero-pad). frag = (kt,nt) 32x16 block, 512 bf16.
// Lane L holds B[kt*32 + (L>>4)*8 + j][nt*16 + (L&15)], j=0..7 -> 16B at L*16.
__global__ void conv_weights(const float* __restrict__ W1, const float* __restrict__ W2,
                             const float* __restrict__ W3, const float* __restrict__ W4,
                             __bf16* __restrict__ ws)
{
  const int f = blockIdx.x;
  const int lane = threadIdx.x;
  int f0, ntot, Ksrc, Nsrc, off;
  const float* W;
  if (f < 48)       { f0 = f;       ntot = 16; Ksrc = 80;  Nsrc = 256; W = W1; off = 0; }
  else if (f < 112) { f0 = f - 48;  ntot = 8;  Ksrc = 256; Nsrc = 128; W = W2; off = 24576; }
  else if (f < 128) { f0 = f - 112; ntot = 4;  Ksrc = 128; Nsrc = 64;  W = W3; off = 57344; }
  else              { f0 = f - 128; ntot = 8;  Ksrc = 64;  Nsrc = 101; W = W4; off = 65536; }
  const int kt = f0 / ntot, nt = f0 % ntot;
  const int q = lane >> 4, c = lane & 15;
  const int n = nt * 16 + c;
  bf16x8 v;
#pragma unroll
  for (int j = 0; j < 8; ++j) {
    const int k = kt * 32 + q * 8 + j;
    const float x = (k < Ksrc && n < Nsrc) ? W[k * Nsrc + n] : 0.f;
    v[j] = (__bf16)x;
  }
  ((bf16x8*)(ws + off))[f0 * 64 + lane] = v;
}

// ---------------- fused forward ------------------------------------------------
// Block: 32 rows, 256 threads (4 waves). Layers 1-3: waves split N; LN in-register
// with cross-wave partial combine in LDS. L4+softmax+projection: waves split
// rows(2) x col-halves(2).

template<int KT, int NTW, int NTOT, int SIN, int SOUT>
__device__ __forceinline__ void layer(
    const __bf16* __restrict__ aIn, __bf16* __restrict__ aOut,
    const bf16x8* __restrict__ Bfrags, int n0t,
    const float* __restrict__ bias, const float* __restrict__ g,
    const float* __restrict__ be,
    float* __restrict__ lnS, float* __restrict__ lnS2,
    float* __restrict__ muS, float* __restrict__ rsS,
    int t, int lane)
{
  const int q = lane >> 4, c = lane & 15;
  const int wv = t >> 6;
  bf16x8 Bf[KT][NTW];
#pragma unroll
  for (int kt = 0; kt < KT; ++kt)
#pragma unroll
    for (int nt = 0; nt < NTW; ++nt)
      Bf[kt][nt] = Bfrags[(kt * NTOT + n0t + nt) * 64 + lane];
  f32x4 acc[2][NTW];
#pragma unroll
  for (int nt = 0; nt < NTW; ++nt) {
    const float bb = bias[(n0t + nt) * 16 + c];
    f32x4 v = {bb, bb, bb, bb};
    acc[0][nt] = v;
    acc[1][nt] = v;
  }
#pragma unroll
  for (int mt = 0; mt < 2; ++mt)
#pragma unroll
    for (int kt = 0; kt < KT; ++kt) {
      const bf16x8 A = *(const bf16x8*)(aIn + (mt * 16 + c) * SIN + kt * 32 + q * 8);
#pragma unroll
      for (int nt = 0; nt < NTW; ++nt)
        acc[mt][nt] = __builtin_amdgcn_mfma_f32_16x16x32_bf16(A, Bf[kt][nt], acc[mt][nt], 0, 0, 0);
    }
  // per-row LN partials over this wave's N-chunk (reduce across the 16 c-lanes)
#pragma unroll
  for (int mt = 0; mt < 2; ++mt)
#pragma unroll
    for (int r = 0; r < 4; ++r) {
      float s = 0.f, s2 = 0.f;
#pragma unroll
      for (int nt = 0; nt < NTW; ++nt) { const float v = acc[mt][nt][r]; s += v; s2 += v * v; }
      s += __shfl_xor(s, 1); s2 += __shfl_xor(s2, 1);
      s += __shfl_xor(s, 2); s2 += __shfl_xor(s2, 2);
      s += __shfl_xor(s, 4); s2 += __shfl_xor(s2, 4);
      s += __shfl_xor(s, 8); s2 += __shfl_xor(s2, 8);
      if (c == 0) {
        const int row = mt * 16 + 4 * q + r;
        lnS[row * 4 + wv] = s;
        lnS2[row * 4 + wv] = s2;
      }
    }
  __syncthreads();
  if (t < 32) {
    const float s  = lnS[t * 4] + lnS[t * 4 + 1] + lnS[t * 4 + 2] + lnS[t * 4 + 3];
    const float s2 = lnS2[t * 4] + lnS2[t * 4 + 1] + lnS2[t * 4 + 2] + lnS2[t * 4 + 3];
    const float invN = 1.f / (float)(NTOT * 16);
    const float mu = s * invN;
    const float var = s2 * invN - mu * mu;
    muS[t] = mu;
    rsS[t] = rsqrtf(var + 1e-5f);
  }
  __syncthreads();
#pragma unroll
  for (int nt = 0; nt < NTW; ++nt) {
    const int col = (n0t + nt) * 16 + c;
    const float gg = g[col], bb = be[col];
#pragma unroll
    for (int mt = 0; mt < 2; ++mt)
#pragma unroll
      for (int r = 0; r < 4; ++r) {
        const int row = mt * 16 + 4 * q + r;
        float v = (acc[mt][nt][r] - muS[row]) * rsS[row] * gg + bb;
        v = v / (1.f + __expf(-v));
        aOut[row * SOUT + col] = (__bf16)v;
      }
  }
  __syncthreads();
}

__global__ __launch_bounds__(256, 4)
void sacq_mfma(const float* __restrict__ obs,  const float* __restrict__ act,
               const float* __restrict__ rew,  const float* __restrict__ boot,
               const float* __restrict__ disc, const float* __restrict__ qsup,
               const float* __restrict__ b1, const float* __restrict__ g1, const float* __restrict__ be1,
               const float* __restrict__ b2, const float* __restrict__ g2, const float* __restrict__ be2,
               const float* __restrict__ b3, const float* __restrict__ g3, const float* __restrict__ be3,
               const float* __restrict__ b4,
               const __bf16* __restrict__ ws,
               float* __restrict__ out)
{
  __shared__ float smf[7152];  // 28608 B
  __bf16* xb = (__bf16*)smf;               // x: 32 x stride 104 (K 80 pad 96)
  __bf16* h2 = (__bf16*)smf;               // h2: 32 x stride 136 (reuses x region)
  __bf16* h1 = (__bf16*)(smf + 2176);      // h1: 32 x stride 264
  __bf16* h3 = (__bf16*)(smf + 2176);      // h3: 32 x stride 72 (after h1 dead)
  float* proj = smf + 3328;                // 32 x stride 104 f32 (overlaps h1 tail)
  float* lnS  = smf + 6656;                // 128
  float* lnS2 = smf + 6784;                // 128
  float* muS  = smf + 6912;                // 32
  float* rsS  = smf + 6944;                // 32
  float* qsL  = smf + 6976;                // 104
  float* rwL  = smf + 7080;                // 32
  float* bdL  = smf + 7112;                // 32

  const int t = threadIdx.x;
  const int lane = t & 63, wv = t >> 6;
  const int q = lane >> 4, c = lane & 15;
  const long row0 = (long)blockIdx.x * 32;

  // ---- prologue: stage x (bf16, zero-pad k 80..103), consts
  for (int idx = t; idx < 32 * 60; idx += 256) {
    const int r = idx / 60, cc = idx - r * 60;
    xb[r * 104 + cc] = (__bf16)obs[row0 * 60 + idx];
  }
  for (int idx = t; idx < 32 * 20; idx += 256) {
    const int r = idx / 20, cc = idx - r * 20;
    xb[r * 104 + 60 + cc] = (__bf16)act[row0 * 20 + idx];
  }
  for (int idx = t; idx < 32 * 24; idx += 256) {
    const int r = idx / 24, cc = idx - r * 24;
    xb[r * 104 + 80 + cc] = (__bf16)0.f;
  }
  if (t < 101) qsL[t] = qsup[t];
  if (t >= 128 && t < 160) {
    const int r = t - 128;
    rwL[r] = rew[row0 + r];
    bdL[r] = boot[row0 + r] * disc[row0 + r];
  }
  __syncthreads();

  const bf16x8* wsf = (const bf16x8*)ws;
  // L1: K=96 (3 kt), N=256, wave chunk = 4 ntiles
  layer<3, 4, 16, 104, 264>(xb, h1, wsf + 0,    wv * 4, b1, g1, be1, lnS, lnS2, muS, rsS, t, lane);
  // L2: K=256 (8 kt), N=128, chunk = 2 ntiles
  layer<8, 2, 8, 264, 136>(h1, h2, wsf + 3072, wv * 2, b2, g2, be2, lnS, lnS2, muS, rsS, t, lane);
  // L3: K=128 (4 kt), N=64, chunk = 1 ntile
  layer<4, 1, 4, 136, 72>(h2, h3, wsf + 7168,  wv,     b3, g3, be3, lnS, lnS2, muS, rsS, t, lane);

  // ---- L4: waves split rows(2) x col-halves(2). N padded to 128 (8 ntiles).
  {
    const int mtw = wv >> 1;
    const int half = wv & 1;
    bf16x8 Bf4[2][4];
#pragma unroll
    for (int kt = 0; kt < 2; ++kt)
#pragma unroll
      for (int nt = 0; nt < 4; ++nt)
        Bf4[kt][nt] = wsf[8192 + (kt * 8 + half * 4 + nt) * 64 + lane];
    f32x4 a4[4];
#pragma unroll
    for (int nt = 0; nt < 4; ++nt) {
      const int col = (half * 4 + nt) * 16 + c;
      const float bb = (col < 101) ? b4[col] : 0.f;
      f32x4 v = {bb, bb, bb, bb};
      a4[nt] = v;
    }
#pragma unroll
    for (int kt = 0; kt < 2; ++kt) {
      const bf16x8 A = *(const bf16x8*)(h3 + (mtw * 16 + c) * 72 + kt * 32 + q * 8);
#pragma unroll
      for (int nt = 0; nt < 4; ++nt)
        a4[nt] = __builtin_amdgcn_mfma_f32_16x16x32_bf16(A, Bf4[kt][nt], a4[nt], 0, 0, 0);
    }
    // softmax: half-max
#pragma unroll
    for (int r = 0; r < 4; ++r) {
      float mx = -3.4e38f;
#pragma unroll
      for (int nt = 0; nt < 4; ++nt) {
        const int col = (half * 4 + nt) * 16 + c;
        if (col < 101) mx = fmaxf(mx, a4[nt][r]);
      }
      mx = fmaxf(mx, __shfl_xor(mx, 1));
      mx = fmaxf(mx, __shfl_xor(mx, 2));
      mx = fmaxf(mx, __shfl_xor(mx, 4));
      mx = fmaxf(mx, __shfl_xor(mx, 8));
      if (c == 0) lnS[(mtw * 16 + 4 * q + r) * 2 + half] = mx;
    }
    __syncthreads();   // h3 reads done; h1 long dead -> safe to zero proj
    for (int idx = t; idx < 32 * 104; idx += 256) proj[idx] = 0.f;
    // exp + half-sum
#pragma unroll
    for (int r = 0; r < 4; ++r) {
      const int row = mtw * 16 + 4 * q + r;
      const float mxf = fmaxf(lnS[row * 2], lnS[row * 2 + 1]);
      float s = 0.f;
#pragma unroll
      for (int nt = 0; nt < 4; ++nt) {
        const int col = (half * 4 + nt) * 16 + c;
        const float e = (col < 101) ? __expf(a4[nt][r] - mxf) : 0.f;
        a4[nt][r] = e;
        s += e;
      }
      s += __shfl_xor(s, 1);
      s += __shfl_xor(s, 2);
      s += __shfl_xor(s, 4);
      s += __shfl_xor(s, 8);
      if (c == 0) lnS2[row * 2 + half] = s;
    }
    __syncthreads();   // proj zeroed + sums ready
    // categorical projection
#pragma unroll
    for (int r = 0; r < 4; ++r) {
      const int row = mtw * 16 + 4 * q + r;
      const float inv = 1.f / (lnS2[row * 2] + lnS2[row * 2 + 1]);
      const float rw = rwL[row], bd = bdL[row];
#pragma unroll
      for (int nt = 0; nt < 4; ++nt) {
        const int col = (half * 4 + nt) * 16 + c;
        if (col < 101) {
          const float p = a4[nt][r] * inv;
          float tz = rw + bd * qsL[col];
          tz = fminf(fmaxf(tz, -10.f), 10.f);
          const float b_ = (tz + 10.f) / 0.2f;
          const float fl = floorf(b_), cl = ceilf(b_);
          int li = (int)fl, ui = (int)cl;
          if (ui == li) { if (li > 0) --li; else ++ui; }
          atomicAdd(&proj[row * 104 + li], p * ((float)ui - b_));
          atomicAdd(&proj[row * 104 + ui], p * (b_ - (float)li));
        }
      }
    }
    __syncthreads();
  }

  // ---- coalesced writeout
  for (int idx = t; idx < 32 * 101; idx += 256) {
    const int r = idx / 101, cc = idx - r * 101;
    out[row0 * 101 + idx] = proj[r * 104 + cc];
  }
}

extern "C" void kernel_launch(void* const* d_in, const int* in_sizes, int n_in,
                              void* d_out, int out_size, void* d_ws, size_t ws_size,
                              hipStream_t stream)
{
  const int B = in_sizes[2];  // rewards: B elements
  __bf16* ws = (__bf16*)d_ws;  // needs 147456 B

  conv_weights<<<dim3(144), dim3(64), 0, stream>>>(
      (const float*)d_in[6], (const float*)d_in[10], (const float*)d_in[14],
      (const float*)d_in[18], ws);

  sacq_mfma<<<dim3(B / 32), dim3(256), 0, stream>>>(
      (const float*)d_in[0],  (const float*)d_in[1],  (const float*)d_in[2],
      (const float*)d_in[3],  (const float*)d_in[4],  (const float*)d_in[5],
      (const float*)d_in[7],  (const float*)d_in[8],  (const float*)d_in[9],
      (const float*)d_in[11], (const float*)d_in[12], (const float*)d_in[13],
      (const float*)d_in[15], (const float*)d_in[16], (const float*)d_in[17],
      (const float*)d_in[19], ws, (float*)d_out);
}

// Round 3
// 333.972 us; speedup vs baseline: 1.9461x; 1.0682x over previous
//
#include <hip/hip_runtime.h>
#include <math.h>

typedef __bf16 bf16x8 __attribute__((ext_vector_type(8)));
typedef float f32x4 __attribute__((ext_vector_type(4)));

// ---------------- weight conversion: fp32 -> bf16 frag-major in d_ws ----------
// Frag (kt,nt) = 32x16 block of B; lane L holds B[kt*32+(L>>4)*8+j][nt*16+(L&15)],
// j=0..7 -> one 16B chunk at L*16. Offsets (bf16 units): L1@0 (96x256, 48 frags),
// L2@24576 (256x128, 64), L3@57344 (128x64, 16), L4@65536 (64x128, 16; N 101->128 pad).
__global__ void conv_weights(const float* __restrict__ W1, const float* __restrict__ W2,
                             const float* __restrict__ W3, const float* __restrict__ W4,
                             __bf16* __restrict__ ws)
{
  const int f = blockIdx.x * 4 + (threadIdx.x >> 6);
  const int lane = threadIdx.x & 63;
  int f0, ntot, Ksrc, Nsrc, off;
  const float* W;
  if (f < 48)       { f0 = f;       ntot = 16; Ksrc = 80;  Nsrc = 256; W = W1; off = 0; }
  else if (f < 112) { f0 = f - 48;  ntot = 8;  Ksrc = 256; Nsrc = 128; W = W2; off = 24576; }
  else if (f < 128) { f0 = f - 112; ntot = 4;  Ksrc = 128; Nsrc = 64;  W = W3; off = 57344; }
  else              { f0 = f - 128; ntot = 8;  Ksrc = 64;  Nsrc = 101; W = W4; off = 65536; }
  const int kt = f0 / ntot, nt = f0 % ntot;
  const int q = lane >> 4, c = lane & 15;
  const int n = nt * 16 + c;
  bf16x8 v;
#pragma unroll
  for (int j = 0; j < 8; ++j) {
    const int k = kt * 32 + q * 8 + j;
    const float x = (k < Ksrc && n < Nsrc) ? W[k * Nsrc + n] : 0.f;
    v[j] = (__bf16)x;
  }
  ((bf16x8*)(ws + off))[f0 * 64 + lane] = v;
}

// ---------------- fused forward: zero-barrier, wave-independent ---------------
// Block = 4 waves x 16 rows = 64 rows. Each wave owns its 16 rows end-to-end:
// all-N MFMA per layer, LN via 4-step shfl butterfly (every lane ends with its
// rows' mu/rsigma), private LDS region for activations. NO __syncthreads.
// Per-wave LDS (bytes): h1 [16][264]bf16 = 8448 | h3 [16][72]bf16 = 2304 (@0,
// h1 dead) + proj [16][101]f32 = 6464 (@2304) ; h2 [16][136]bf16 = 4352 (@8768).
// Total 13120 B/wave, 52480/block -> 3 blocks/CU (12 waves/CU).

__global__ __launch_bounds__(256, 3)
void sacq_wave(const float* __restrict__ obs,  const float* __restrict__ act,
               const float* __restrict__ rew,  const float* __restrict__ boot,
               const float* __restrict__ disc, const float* __restrict__ qsup,
               const float* __restrict__ b1, const float* __restrict__ g1, const float* __restrict__ be1,
               const float* __restrict__ b2, const float* __restrict__ g2, const float* __restrict__ be2,
               const float* __restrict__ b3, const float* __restrict__ g3, const float* __restrict__ be3,
               const float* __restrict__ b4,
               const __bf16* __restrict__ ws,
               float* __restrict__ out)
{
  __shared__ float sm[13120];
  const int t = threadIdx.x;
  const int wv = t >> 6, lane = t & 63;
  const int q = lane >> 4, c = lane & 15;
  float* smw = sm + wv * 3280;
  __bf16* h1 = (__bf16*)smw;             // [16][264]
  __bf16* h2 = (__bf16*)(smw + 2192);    // [16][136]
  __bf16* h3 = (__bf16*)smw;             // [16][72]   (after h1 dead)
  float*  proj = smw + 576;              // [16][101]  (after h1 dead)
  const int row0w = blockIdx.x * 64 + wv * 16;
  const bf16x8* wsf = (const bf16x8*)ws;

  // ================= Layer 1: x[16x80] @ W1 -> 256, LN+SiLU =================
  {
    bf16x8 A1[3];
    const float* obsR = obs + (size_t)(row0w + c) * 60;
    const float* actR = act + (size_t)(row0w + c) * 20;
#pragma unroll
    for (int kt = 0; kt < 3; ++kt)
#pragma unroll
      for (int j = 0; j < 8; ++j) {
        const int k = kt * 32 + q * 8 + j;
        float xv = 0.f;
        if (k < 60) xv = obsR[k];
        else if (k < 80) xv = actR[k - 60];
        A1[kt][j] = (__bf16)xv;
      }
    f32x4 acc1[16];
#pragma unroll
    for (int nt = 0; nt < 16; ++nt) {
      const float bb = b1[nt * 16 + c];
      f32x4 v = {bb, bb, bb, bb};
      acc1[nt] = v;
    }
#pragma unroll
    for (int kt = 0; kt < 3; ++kt)
#pragma unroll
      for (int nt = 0; nt < 16; ++nt)
        acc1[nt] = __builtin_amdgcn_mfma_f32_16x16x32_bf16(A1[kt], wsf[(kt * 16 + nt) * 64 + lane], acc1[nt], 0, 0, 0);

    float mu[4], rs[4];
#pragma unroll
    for (int r = 0; r < 4; ++r) {
      float s = 0.f, s2 = 0.f;
#pragma unroll
      for (int nt = 0; nt < 16; ++nt) { const float v = acc1[nt][r]; s += v; s2 += v * v; }
      s += __shfl_xor(s, 1); s2 += __shfl_xor(s2, 1);
      s += __shfl_xor(s, 2); s2 += __shfl_xor(s2, 2);
      s += __shfl_xor(s, 4); s2 += __shfl_xor(s2, 4);
      s += __shfl_xor(s, 8); s2 += __shfl_xor(s2, 8);
      const float m = s * (1.f / 256.f);
      mu[r] = m;
      rs[r] = rsqrtf(s2 * (1.f / 256.f) - m * m + 1e-5f);
    }
#pragma unroll
    for (int nt = 0; nt < 16; ++nt) {
      const int col = nt * 16 + c;
      const float gg = g1[col], bb = be1[col];
#pragma unroll
      for (int r = 0; r < 4; ++r) {
        float v = (acc1[nt][r] - mu[r]) * rs[r] * gg + bb;
        v = v * __builtin_amdgcn_rcpf(1.f + __expf(-v));
        h1[(4 * q + r) * 264 + col] = (__bf16)v;
      }
    }
  }

  // ================= Layer 2: 256 -> 128, LN+SiLU =================
  {
    f32x4 acc2[8];
#pragma unroll
    for (int nt = 0; nt < 8; ++nt) {
      const float bb = b2[nt * 16 + c];
      f32x4 v = {bb, bb, bb, bb};
      acc2[nt] = v;
    }
#pragma unroll
    for (int kt = 0; kt < 8; ++kt) {
      const bf16x8 A2 = *(const bf16x8*)(h1 + c * 264 + kt * 32 + q * 8);
#pragma unroll
      for (int nt = 0; nt < 8; ++nt)
        acc2[nt] = __builtin_amdgcn_mfma_f32_16x16x32_bf16(A2, wsf[3072 + (kt * 8 + nt) * 64 + lane], acc2[nt], 0, 0, 0);
    }
    float mu[4], rs[4];
#pragma unroll
    for (int r = 0; r < 4; ++r) {
      float s = 0.f, s2 = 0.f;
#pragma unroll
      for (int nt = 0; nt < 8; ++nt) { const float v = acc2[nt][r]; s += v; s2 += v * v; }
      s += __shfl_xor(s, 1); s2 += __shfl_xor(s2, 1);
      s += __shfl_xor(s, 2); s2 += __shfl_xor(s2, 2);
      s += __shfl_xor(s, 4); s2 += __shfl_xor(s2, 4);
      s += __shfl_xor(s, 8); s2 += __shfl_xor(s2, 8);
      const float m = s * (1.f / 128.f);
      mu[r] = m;
      rs[r] = rsqrtf(s2 * (1.f / 128.f) - m * m + 1e-5f);
    }
#pragma unroll
    for (int nt = 0; nt < 8; ++nt) {
      const int col = nt * 16 + c;
      const float gg = g2[col], bb = be2[col];
#pragma unroll
      for (int r = 0; r < 4; ++r) {
        float v = (acc2[nt][r] - mu[r]) * rs[r] * gg + bb;
        v = v * __builtin_amdgcn_rcpf(1.f + __expf(-v));
        h2[(4 * q + r) * 136 + col] = (__bf16)v;
      }
    }
  }

  // ================= Layer 3: 128 -> 64, LN+SiLU =================
  {
    f32x4 acc3[4];
#pragma unroll
    for (int nt = 0; nt < 4; ++nt) {
      const float bb = b3[nt * 16 + c];
      f32x4 v = {bb, bb, bb, bb};
      acc3[nt] = v;
    }
#pragma unroll
    for (int kt = 0; kt < 4; ++kt) {
      const bf16x8 A3 = *(const bf16x8*)(h2 + c * 136 + kt * 32 + q * 8);
#pragma unroll
      for (int nt = 0; nt < 4; ++nt)
        acc3[nt] = __builtin_amdgcn_mfma_f32_16x16x32_bf16(A3, wsf[7168 + (kt * 4 + nt) * 64 + lane], acc3[nt], 0, 0, 0);
    }
    float mu[4], rs[4];
#pragma unroll
    for (int r = 0; r < 4; ++r) {
      float s = 0.f, s2 = 0.f;
#pragma unroll
      for (int nt = 0; nt < 4; ++nt) { const float v = acc3[nt][r]; s += v; s2 += v * v; }
      s += __shfl_xor(s, 1); s2 += __shfl_xor(s2, 1);
      s += __shfl_xor(s, 2); s2 += __shfl_xor(s2, 2);
      s += __shfl_xor(s, 4); s2 += __shfl_xor(s2, 4);
      s += __shfl_xor(s, 8); s2 += __shfl_xor(s2, 8);
      const float m = s * (1.f / 64.f);
      mu[r] = m;
      rs[r] = rsqrtf(s2 * (1.f / 64.f) - m * m + 1e-5f);
    }
#pragma unroll
    for (int nt = 0; nt < 4; ++nt) {
      const int col = nt * 16 + c;
      const float gg = g3[col], bb = be3[col];
#pragma unroll
      for (int r = 0; r < 4; ++r) {
        float v = (acc3[nt][r] - mu[r]) * rs[r] * gg + bb;
        v = v * __builtin_amdgcn_rcpf(1.f + __expf(-v));
        h3[(4 * q + r) * 72 + col] = (__bf16)v;
      }
    }
  }

  // ================= Layer 4 (101 cols, 7 ntiles) + softmax + projection =====
  {
    f32x4 a4[7];
#pragma unroll
    for (int nt = 0; nt < 7; ++nt) {
      const int col = nt * 16 + c;
      const float bb = (col < 101) ? b4[col] : 0.f;
      f32x4 v = {bb, bb, bb, bb};
      a4[nt] = v;
    }
#pragma unroll
    for (int kt = 0; kt < 2; ++kt) {
      const bf16x8 A4 = *(const bf16x8*)(h3 + c * 72 + kt * 32 + q * 8);
#pragma unroll
      for (int nt = 0; nt < 7; ++nt)
        a4[nt] = __builtin_amdgcn_mfma_f32_16x16x32_bf16(A4, wsf[8192 + (kt * 8 + nt) * 64 + lane], a4[nt], 0, 0, 0);
    }

    // zero proj (h1 region is dead; in-wave DS ordering makes this safe)
    {
      f32x4 z = {0.f, 0.f, 0.f, 0.f};
      f32x4* p4 = (f32x4*)proj;
      for (int i = lane; i < 404; i += 64) p4[i] = z;
    }

    // softmax over 101 atoms per row, fully in-register
    float mx4[4] = {-3.4e38f, -3.4e38f, -3.4e38f, -3.4e38f};
#pragma unroll
    for (int nt = 0; nt < 7; ++nt) {
      const bool ok = (nt < 6) | (c < 5);
#pragma unroll
      for (int r = 0; r < 4; ++r)
        if (ok) mx4[r] = fmaxf(mx4[r], a4[nt][r]);
    }
#pragma unroll
    for (int r = 0; r < 4; ++r) {
      mx4[r] = fmaxf(mx4[r], __shfl_xor(mx4[r], 1));
      mx4[r] = fmaxf(mx4[r], __shfl_xor(mx4[r], 2));
      mx4[r] = fmaxf(mx4[r], __shfl_xor(mx4[r], 4));
      mx4[r] = fmaxf(mx4[r], __shfl_xor(mx4[r], 8));
    }
    float sm4[4] = {0.f, 0.f, 0.f, 0.f};
#pragma unroll
    for (int nt = 0; nt < 7; ++nt) {
      const bool ok = (nt < 6) | (c < 5);
#pragma unroll
      for (int r = 0; r < 4; ++r) {
        const float e = ok ? __expf(a4[nt][r] - mx4[r]) : 0.f;
        a4[nt][r] = e;
        sm4[r] += e;
      }
    }
    float inv4[4];
#pragma unroll
    for (int r = 0; r < 4; ++r) {
      float s = sm4[r];
      s += __shfl_xor(s, 1);
      s += __shfl_xor(s, 2);
      s += __shfl_xor(s, 4);
      s += __shfl_xor(s, 8);
      inv4[r] = __builtin_amdgcn_rcpf(s);
    }

    // per-row constants straight from global (L1-cached)
    float rwv[4], bdv[4];
#pragma unroll
    for (int r = 0; r < 4; ++r) {
      const int gr = row0w + 4 * q + r;
      rwv[r] = rew[gr];
      bdv[r] = boot[gr] * disc[gr];
    }

    // categorical projection: wave-private LDS atomics
#pragma unroll
    for (int nt = 0; nt < 7; ++nt) {
      const int col = nt * 16 + c;
      if ((nt < 6) | (c < 5)) {
        const float qsv = qsup[col];
#pragma unroll
        for (int r = 0; r < 4; ++r) {
          const float p = a4[nt][r] * inv4[r];
          float tz = rwv[r] + bdv[r] * qsv;
          tz = fminf(fmaxf(tz, -10.f), 10.f);
          const float b_ = (tz + 10.f) * 5.f;
          const float fl = floorf(b_), cl = ceilf(b_);
          int li = (int)fl, ui = (int)cl;
          if (ui == li) { if (li > 0) --li; else ++ui; }
          const int rb = (4 * q + r) * 101;
          atomicAdd(&proj[rb + li], p * ((float)ui - b_));
          atomicAdd(&proj[rb + ui], p * (b_ - (float)li));
        }
      }
    }
  }

  // ---- coalesced float4 writeout of this wave's 16x101 block
  {
    const f32x4* p4 = (const f32x4*)proj;
    f32x4* o4 = (f32x4*)(out + (size_t)row0w * 101);
    for (int i = lane; i < 404; i += 64) o4[i] = p4[i];
  }
}

extern "C" void kernel_launch(void* const* d_in, const int* in_sizes, int n_in,
                              void* d_out, int out_size, void* d_ws, size_t ws_size,
                              hipStream_t stream)
{
  const int B = in_sizes[2];  // rewards: B elements
  __bf16* ws = (__bf16*)d_ws; // 147456 B used

  conv_weights<<<dim3(36), dim3(256), 0, stream>>>(
      (const float*)d_in[6], (const float*)d_in[10], (const float*)d_in[14],
      (const float*)d_in[18], ws);

  sacq_wave<<<dim3(B / 64), dim3(256), 0, stream>>>(
      (const float*)d_in[0],  (const float*)d_in[1],  (const float*)d_in[2],
      (const float*)d_in[3],  (const float*)d_in[4],  (const float*)d_in[5],
      (const float*)d_in[7],  (const float*)d_in[8],  (const float*)d_in[9],
      (const float*)d_in[11], (const float*)d_in[12], (const float*)d_in[13],
      (const float*)d_in[15], (const float*)d_in[16], (const float*)d_in[17],
      (const float*)d_in[19], ws, (float*)d_out);
}

// Round 4
// 329.548 us; speedup vs baseline: 1.9722x; 1.0134x over previous
//
#include <hip/hip_runtime.h>
#include <math.h>

typedef __bf16 bf16x8 __attribute__((ext_vector_type(8)));
typedef float f32x4 __attribute__((ext_vector_type(4)));

// ---------------- weight conversion: fp32 -> bf16 frag-major in d_ws ----------
// Frag (kt,nt) = 32x16 block of B; lane L holds B[kt*32+(L>>4)*8+j][nt*16+(L&15)],
// j=0..7 -> one 16B chunk at L*16. Offsets (bf16 units): L1@0 (96x256, 48 frags),
// L2@24576 (256x128, 64), L3@57344 (128x64, 16), L4@65536 (64x128, 16; N 101->128 pad).
__global__ void conv_weights(const float* __restrict__ W1, const float* __restrict__ W2,
                             const float* __restrict__ W3, const float* __restrict__ W4,
                             __bf16* __restrict__ ws)
{
  const int f = blockIdx.x * 4 + (threadIdx.x >> 6);
  const int lane = threadIdx.x & 63;
  int f0, ntot, Ksrc, Nsrc, off;
  const float* W;
  if (f < 48)       { f0 = f;       ntot = 16; Ksrc = 80;  Nsrc = 256; W = W1; off = 0; }
  else if (f < 112) { f0 = f - 48;  ntot = 8;  Ksrc = 256; Nsrc = 128; W = W2; off = 24576; }
  else if (f < 128) { f0 = f - 112; ntot = 4;  Ksrc = 128; Nsrc = 64;  W = W3; off = 57344; }
  else              { f0 = f - 128; ntot = 8;  Ksrc = 64;  Nsrc = 101; W = W4; off = 65536; }
  const int kt = f0 / ntot, nt = f0 % ntot;
  const int q = lane >> 4, c = lane & 15;
  const int n = nt * 16 + c;
  bf16x8 v;
#pragma unroll
  for (int j = 0; j < 8; ++j) {
    const int k = kt * 32 + q * 8 + j;
    const float x = (k < Ksrc && n < Nsrc) ? W[k * Nsrc + n] : 0.f;
    v[j] = (__bf16)x;
  }
  ((bf16x8*)(ws + off))[f0 * 64 + lane] = v;
}

// ---------------- fused forward: zero-barrier + register burst prefetch -------
// Block = 4 waves x 16 rows. Each wave owns its rows end-to-end; B-fragments are
// loaded in explicit register bursts (12-16 dwordx4 in flight) so MFMA never
// waits on a just-issued load. L2 layer uses depth-2 kt prefetch.
// Per-wave LDS as round 3: 13120 B/wave, 52480/block -> 3 blocks/CU.

__global__ __launch_bounds__(256, 3)
void sacq_wave(const float* __restrict__ obs,  const float* __restrict__ act,
               const float* __restrict__ rew,  const float* __restrict__ boot,
               const float* __restrict__ disc, const float* __restrict__ qsup,
               const float* __restrict__ b1, const float* __restrict__ g1, const float* __restrict__ be1,
               const float* __restrict__ b2, const float* __restrict__ g2, const float* __restrict__ be2,
               const float* __restrict__ b3, const float* __restrict__ g3, const float* __restrict__ be3,
               const float* __restrict__ b4,
               const __bf16* __restrict__ ws,
               float* __restrict__ out)
{
  __shared__ float sm[13120];
  const int t = threadIdx.x;
  const int wv = t >> 6, lane = t & 63;
  const int q = lane >> 4, c = lane & 15;
  float* smw = sm + wv * 3280;
  __bf16* h1 = (__bf16*)smw;             // [16][264]
  __bf16* h2 = (__bf16*)(smw + 2192);    // [16][136]
  __bf16* h3 = (__bf16*)smw;             // [16][72]   (after h1 dead)
  float*  proj = smw + 576;              // [16][101]  (after h1 dead)
  const int row0w = blockIdx.x * 64 + wv * 16;
  const bf16x8* wsf = (const bf16x8*)ws;

  // ================= Layer 1: x[16x80] @ W1 -> 256, LN+SiLU =================
  f32x4 acc1[16];
  {
    // ---- A fragments via float4 loads (rows are 240B/80B strided, 16B aligned)
    bf16x8 A1[3];
    const float4* ob4 = (const float4*)(obs + (size_t)(row0w + c) * 60);
    const float4* ac4 = (const float4*)(act + (size_t)(row0w + c) * 20);
#pragma unroll
    for (int kt = 0; kt < 3; ++kt) {
      const int k0 = kt * 32 + q * 8;
      float v[8];
      if (k0 < 56) {
        const float4 a = ob4[k0 / 4], b = ob4[k0 / 4 + 1];
        v[0]=a.x; v[1]=a.y; v[2]=a.z; v[3]=a.w; v[4]=b.x; v[5]=b.y; v[6]=b.z; v[7]=b.w;
      } else if (k0 == 56) {
        const float4 a = ob4[14], b = ac4[0];
        v[0]=a.x; v[1]=a.y; v[2]=a.z; v[3]=a.w; v[4]=b.x; v[5]=b.y; v[6]=b.z; v[7]=b.w;
      } else if (k0 < 80) {
        const float4 a = ac4[(k0 - 60) / 4], b = ac4[(k0 - 60) / 4 + 1];
        v[0]=a.x; v[1]=a.y; v[2]=a.z; v[3]=a.w; v[4]=b.x; v[5]=b.y; v[6]=b.z; v[7]=b.w;
      } else {
#pragma unroll
        for (int j = 0; j < 8; ++j) v[j] = 0.f;
      }
#pragma unroll
      for (int j = 0; j < 8; ++j) A1[kt][j] = (__bf16)v[j];
    }
#pragma unroll
    for (int nt = 0; nt < 16; ++nt) {
      const float bb = b1[nt * 16 + c];
      f32x4 vv = {bb, bb, bb, bb};
      acc1[nt] = vv;
    }
    // ---- 4 chunks of 4 ntiles; each chunk: burst 12 frag loads, then 12 MFMAs
#pragma unroll
    for (int ch = 0; ch < 4; ++ch) {
      bf16x8 Bb[3][4];
#pragma unroll
      for (int kt = 0; kt < 3; ++kt)
#pragma unroll
        for (int j = 0; j < 4; ++j)
          Bb[kt][j] = wsf[(kt * 16 + ch * 4 + j) * 64 + lane];
#pragma unroll
      for (int kt = 0; kt < 3; ++kt)
#pragma unroll
        for (int j = 0; j < 4; ++j)
          acc1[ch * 4 + j] = __builtin_amdgcn_mfma_f32_16x16x32_bf16(A1[kt], Bb[kt][j], acc1[ch * 4 + j], 0, 0, 0);
    }
    float mu[4], rs[4];
#pragma unroll
    for (int r = 0; r < 4; ++r) {
      float s = 0.f, s2 = 0.f;
#pragma unroll
      for (int nt = 0; nt < 16; ++nt) { const float v = acc1[nt][r]; s += v; s2 += v * v; }
      s += __shfl_xor(s, 1); s2 += __shfl_xor(s2, 1);
      s += __shfl_xor(s, 2); s2 += __shfl_xor(s2, 2);
      s += __shfl_xor(s, 4); s2 += __shfl_xor(s2, 4);
      s += __shfl_xor(s, 8); s2 += __shfl_xor(s2, 8);
      const float m = s * (1.f / 256.f);
      mu[r] = m;
      rs[r] = rsqrtf(s2 * (1.f / 256.f) - m * m + 1e-5f);
    }
#pragma unroll
    for (int nt = 0; nt < 16; ++nt) {
      const int col = nt * 16 + c;
      const float gg = g1[col], bb = be1[col];
#pragma unroll
      for (int r = 0; r < 4; ++r) {
        float v = (acc1[nt][r] - mu[r]) * rs[r] * gg + bb;
        v = v * __builtin_amdgcn_rcpf(1.f + __expf(-v));
        h1[(4 * q + r) * 264 + col] = (__bf16)v;
      }
    }
  }

  // ================= Layer 2: 256 -> 128, LN+SiLU (depth-2 kt prefetch) ======
  {
    f32x4 acc2[8];
#pragma unroll
    for (int nt = 0; nt < 8; ++nt) {
      const float bb = b2[nt * 16 + c];
      f32x4 vv = {bb, bb, bb, bb};
      acc2[nt] = vv;
    }
    bf16x8 B2[3][8];
#pragma unroll
    for (int nt = 0; nt < 8; ++nt) B2[0][nt] = wsf[3072 + (0 * 8 + nt) * 64 + lane];
#pragma unroll
    for (int nt = 0; nt < 8; ++nt) B2[1][nt] = wsf[3072 + (1 * 8 + nt) * 64 + lane];
#pragma unroll
    for (int kt = 0; kt < 8; ++kt) {
      if (kt + 2 < 8) {
#pragma unroll
        for (int nt = 0; nt < 8; ++nt)
          B2[(kt + 2) % 3][nt] = wsf[3072 + ((kt + 2) * 8 + nt) * 64 + lane];
      }
      const bf16x8 A2 = *(const bf16x8*)(h1 + c * 264 + kt * 32 + q * 8);
#pragma unroll
      for (int nt = 0; nt < 8; ++nt)
        acc2[nt] = __builtin_amdgcn_mfma_f32_16x16x32_bf16(A2, B2[kt % 3][nt], acc2[nt], 0, 0, 0);
    }
    float mu[4], rs[4];
#pragma unroll
    for (int r = 0; r < 4; ++r) {
      float s = 0.f, s2 = 0.f;
#pragma unroll
      for (int nt = 0; nt < 8; ++nt) { const float v = acc2[nt][r]; s += v; s2 += v * v; }
      s += __shfl_xor(s, 1); s2 += __shfl_xor(s2, 1);
      s += __shfl_xor(s, 2); s2 += __shfl_xor(s2, 2);
      s += __shfl_xor(s, 4); s2 += __shfl_xor(s2, 4);
      s += __shfl_xor(s, 8); s2 += __shfl_xor(s2, 8);
      const float m = s * (1.f / 128.f);
      mu[r] = m;
      rs[r] = rsqrtf(s2 * (1.f / 128.f) - m * m + 1e-5f);
    }
#pragma unroll
    for (int nt = 0; nt < 8; ++nt) {
      const int col = nt * 16 + c;
      const float gg = g2[col], bb = be2[col];
#pragma unroll
      for (int r = 0; r < 4; ++r) {
        float v = (acc2[nt][r] - mu[r]) * rs[r] * gg + bb;
        v = v * __builtin_amdgcn_rcpf(1.f + __expf(-v));
        h2[(4 * q + r) * 136 + col] = (__bf16)v;
      }
    }
  }

  // ================= Layer 3: 128 -> 64, LN+SiLU (full 16-frag burst) ========
  {
    bf16x8 B3[4][4];
#pragma unroll
    for (int kt = 0; kt < 4; ++kt)
#pragma unroll
      for (int nt = 0; nt < 4; ++nt)
        B3[kt][nt] = wsf[7168 + (kt * 4 + nt) * 64 + lane];
    f32x4 acc3[4];
#pragma unroll
    for (int nt = 0; nt < 4; ++nt) {
      const float bb = b3[nt * 16 + c];
      f32x4 vv = {bb, bb, bb, bb};
      acc3[nt] = vv;
    }
#pragma unroll
    for (int kt = 0; kt < 4; ++kt) {
      const bf16x8 A3 = *(const bf16x8*)(h2 + c * 136 + kt * 32 + q * 8);
#pragma unroll
      for (int nt = 0; nt < 4; ++nt)
        acc3[nt] = __builtin_amdgcn_mfma_f32_16x16x32_bf16(A3, B3[kt][nt], acc3[nt], 0, 0, 0);
    }
    float mu[4], rs[4];
#pragma unroll
    for (int r = 0; r < 4; ++r) {
      float s = 0.f, s2 = 0.f;
#pragma unroll
      for (int nt = 0; nt < 4; ++nt) { const float v = acc3[nt][r]; s += v; s2 += v * v; }
      s += __shfl_xor(s, 1); s2 += __shfl_xor(s2, 1);
      s += __shfl_xor(s, 2); s2 += __shfl_xor(s2, 2);
      s += __shfl_xor(s, 4); s2 += __shfl_xor(s2, 4);
      s += __shfl_xor(s, 8); s2 += __shfl_xor(s2, 8);
      const float m = s * (1.f / 64.f);
      mu[r] = m;
      rs[r] = rsqrtf(s2 * (1.f / 64.f) - m * m + 1e-5f);
    }
#pragma unroll
    for (int nt = 0; nt < 4; ++nt) {
      const int col = nt * 16 + c;
      const float gg = g3[col], bb = be3[col];
#pragma unroll
      for (int r = 0; r < 4; ++r) {
        float v = (acc3[nt][r] - mu[r]) * rs[r] * gg + bb;
        v = v * __builtin_amdgcn_rcpf(1.f + __expf(-v));
        h3[(4 * q + r) * 72 + col] = (__bf16)v;
      }
    }
  }

  // ================= Layer 4 (101 cols) + softmax + projection ===============
  {
    bf16x8 B4[2][7];
#pragma unroll
    for (int kt = 0; kt < 2; ++kt)
#pragma unroll
      for (int nt = 0; nt < 7; ++nt)
        B4[kt][nt] = wsf[8192 + (kt * 8 + nt) * 64 + lane];
    f32x4 a4[7];
#pragma unroll
    for (int nt = 0; nt < 7; ++nt) {
      const int col = nt * 16 + c;
      const float bb = (col < 101) ? b4[col] : 0.f;
      f32x4 vv = {bb, bb, bb, bb};
      a4[nt] = vv;
    }
#pragma unroll
    for (int kt = 0; kt < 2; ++kt) {
      const bf16x8 A4 = *(const bf16x8*)(h3 + c * 72 + kt * 32 + q * 8);
#pragma unroll
      for (int nt = 0; nt < 7; ++nt)
        a4[nt] = __builtin_amdgcn_mfma_f32_16x16x32_bf16(A4, B4[kt][nt], a4[nt], 0, 0, 0);
    }

    // zero proj (h1 region dead; in-wave DS ordering makes this safe)
    {
      f32x4 z = {0.f, 0.f, 0.f, 0.f};
      f32x4* p4 = (f32x4*)proj;
      for (int i = lane; i < 404; i += 64) p4[i] = z;
    }

    // softmax over 101 atoms per row, fully in-register
    float mx4[4] = {-3.4e38f, -3.4e38f, -3.4e38f, -3.4e38f};
#pragma unroll
    for (int nt = 0; nt < 7; ++nt) {
      const bool ok = (nt < 6) | (c < 5);
#pragma unroll
      for (int r = 0; r < 4; ++r)
        if (ok) mx4[r] = fmaxf(mx4[r], a4[nt][r]);
    }
#pragma unroll
    for (int r = 0; r < 4; ++r) {
      mx4[r] = fmaxf(mx4[r], __shfl_xor(mx4[r], 1));
      mx4[r] = fmaxf(mx4[r], __shfl_xor(mx4[r], 2));
      mx4[r] = fmaxf(mx4[r], __shfl_xor(mx4[r], 4));
      mx4[r] = fmaxf(mx4[r], __shfl_xor(mx4[r], 8));
    }
    float sm4[4] = {0.f, 0.f, 0.f, 0.f};
#pragma unroll
    for (int nt = 0; nt < 7; ++nt) {
      const bool ok = (nt < 6) | (c < 5);
#pragma unroll
      for (int r = 0; r < 4; ++r) {
        const float e = ok ? __expf(a4[nt][r] - mx4[r]) : 0.f;
        a4[nt][r] = e;
        sm4[r] += e;
      }
    }
    float inv4[4];
#pragma unroll
    for (int r = 0; r < 4; ++r) {
      float s = sm4[r];
      s += __shfl_xor(s, 1);
      s += __shfl_xor(s, 2);
      s += __shfl_xor(s, 4);
      s += __shfl_xor(s, 8);
      inv4[r] = __builtin_amdgcn_rcpf(s);
    }

    float rwv[4], bdv[4];
#pragma unroll
    for (int r = 0; r < 4; ++r) {
      const int gr = row0w + 4 * q + r;
      rwv[r] = rew[gr];
      bdv[r] = boot[gr] * disc[gr];
    }

    // categorical projection: wave-private LDS atomics
#pragma unroll
    for (int nt = 0; nt < 7; ++nt) {
      const int col = nt * 16 + c;
      if ((nt < 6) | (c < 5)) {
        const float qsv = qsup[col];
#pragma unroll
        for (int r = 0; r < 4; ++r) {
          const float p = a4[nt][r] * inv4[r];
          float tz = rwv[r] + bdv[r] * qsv;
          tz = fminf(fmaxf(tz, -10.f), 10.f);
          const float b_ = (tz + 10.f) * 5.f;
          const float fl = floorf(b_), cl = ceilf(b_);
          int li = (int)fl, ui = (int)cl;
          if (ui == li) { if (li > 0) --li; else ++ui; }
          const int rb = (4 * q + r) * 101;
          atomicAdd(&proj[rb + li], p * ((float)ui - b_));
          atomicAdd(&proj[rb + ui], p * (b_ - (float)li));
        }
      }
    }
  }

  // ---- coalesced float4 writeout of this wave's 16x101 block
  {
    const f32x4* p4 = (const f32x4*)proj;
    f32x4* o4 = (f32x4*)(out + (size_t)row0w * 101);
    for (int i = lane; i < 404; i += 64) o4[i] = p4[i];
  }
}

extern "C" void kernel_launch(void* const* d_in, const int* in_sizes, int n_in,
                              void* d_out, int out_size, void* d_ws, size_t ws_size,
                              hipStream_t stream)
{
  const int B = in_sizes[2];  // rewards: B elements
  __bf16* ws = (__bf16*)d_ws; // 147456 B used

  conv_weights<<<dim3(36), dim3(256), 0, stream>>>(
      (const float*)d_in[6], (const float*)d_in[10], (const float*)d_in[14],
      (const float*)d_in[18], ws);

  sacq_wave<<<dim3(B / 64), dim3(256), 0, stream>>>(
      (const float*)d_in[0],  (const float*)d_in[1],  (const float*)d_in[2],
      (const float*)d_in[3],  (const float*)d_in[4],  (const float*)d_in[5],
      (const float*)d_in[7],  (const float*)d_in[8],  (const float*)d_in[9],
      (const float*)d_in[11], (const float*)d_in[12], (const float*)d_in[13],
      (const float*)d_in[15], (const float*)d_in[16], (const float*)d_in[17],
      (const float*)d_in[19], ws, (float*)d_out);
}